// Round 6
// baseline (1101.283 us; speedup 1.0000x reference)
//
#include <hip/hip_runtime.h>

#define NN    100000
#define NE    3200000
#define DIMK  512
#define HIDN  16
#define NCLS  64
#define NBUCK 391        // ceil(NN / 256) coarse buckets (dest >> 8)
#define NBLK  512        // coarse-pass chunks
#define CHUNK 6250       // NE / NBLK exactly

// ---- threefry2x32-20, JAX partitionable 32-bit path: bits = x0_final ^ x1_final,
// key=(0,42), counter=(0, i). Verified (absmax 0.031).
__device__ __forceinline__ unsigned rotl32(unsigned x, int r){ return (x << r) | (x >> (32 - r)); }

__device__ __forceinline__ unsigned threefry_bits(unsigned i){
  const unsigned k0 = 0u, k1 = 42u;
  const unsigned k2 = 0x1BD11BDAu ^ k0 ^ k1;
  unsigned a = 0u + k0, b = i + k1;
#define TF_R(r) { a += b; b = rotl32(b, (r)); b ^= a; }
  TF_R(13) TF_R(15) TF_R(26) TF_R(6)  a += k1; b += k2 + 1u;
  TF_R(17) TF_R(29) TF_R(16) TF_R(24) a += k2; b += k0 + 2u;
  TF_R(13) TF_R(15) TF_R(26) TF_R(6)  a += k0; b += k1 + 3u;
  TF_R(17) TF_R(29) TF_R(16) TF_R(24) a += k1; b += k2 + 4u;
  TF_R(13) TF_R(15) TF_R(26) TF_R(6)  a += k2; b += k0 + 5u;
#undef TF_R
  return a ^ b;   // keep iff !(bits & 0x80000000)
}

// ---- k_front: fused {kp1 coarse histogram} + {h1 = x@W1 (RAW, fp16)} ----
// Independent workloads; gemm's 205 MB x-read overlaps the histogram pass.
__global__ __launch_bounds__(256) void k_front(const float* __restrict__ x,
                                               const float* __restrict__ W1,
                                               const int* __restrict__ col,
                                               int* __restrict__ M,
                                               _Float16* __restrict__ h1){
  __shared__ int h[NBUCK];
  if (blockIdx.x < NBLK){
    // ---- coarse histogram for chunk blockIdx.x ----
    const int blk = blockIdx.x, t = threadIdx.x;
    for (int q = t; q < NBUCK; q += 256) h[q] = 0;
    __syncthreads();
    const int e0 = blk * CHUNK;
    for (int i = t; i < CHUNK; i += 256)
      atomicAdd(&h[col[e0 + i] >> 8], 1);
    __syncthreads();
    for (int q = t; q < NBUCK; q += 256) M[blk * NBUCK + q] = h[q];
    return;
  }
  // ---- gemm: wave per node, raw h1 (dis applied later at gather time) ----
  const int lane = threadIdx.x & 63;
  const int wid  = (blockIdx.x - NBLK) * 4 + (threadIdx.x >> 6);
  const int nw   = 1024 * 4;
  const bool s5 = (lane & 32) != 0;
  const bool s4 = (lane & 16) != 0;
  const bool s3 = (lane & 8)  != 0;
  const bool s2 = (lane & 4)  != 0;

  float4 w4[8][4];
  const float4* W1v = (const float4*)W1;
#pragma unroll
  for (int k = 0; k < 8; ++k)
#pragma unroll
    for (int jj = 0; jj < 4; ++jj)
      w4[k][jj] = W1v[(lane * 8 + k) * 4 + jj];

  for (int n = wid; n < NN; n += nw){
    const float4* xp = (const float4*)(x + (size_t)n * DIMK + lane * 8);
    float4 xa = xp[0], xb = xp[1];
    float xv[8] = {xa.x, xa.y, xa.z, xa.w, xb.x, xb.y, xb.z, xb.w};
    float acc[16];
#pragma unroll
    for (int j = 0; j < 16; ++j) acc[j] = 0.f;
#pragma unroll
    for (int k = 0; k < 8; ++k){
      float xk = xv[k];
#pragma unroll
      for (int jj = 0; jj < 4; ++jj){
        acc[jj*4+0] = fmaf(xk, w4[k][jj].x, acc[jj*4+0]);
        acc[jj*4+1] = fmaf(xk, w4[k][jj].y, acc[jj*4+1]);
        acc[jj*4+2] = fmaf(xk, w4[k][jj].z, acc[jj*4+2]);
        acc[jj*4+3] = fmaf(xk, w4[k][jj].w, acc[jj*4+3]);
      }
    }
    float t8[8];
#pragma unroll
    for (int m = 0; m < 8; ++m){
      float keep = s5 ? acc[8+m] : acc[m];
      float give = s5 ? acc[m]   : acc[8+m];
      t8[m] = keep + __shfl_xor(give, 32, 64);
    }
    float t4[4];
#pragma unroll
    for (int m = 0; m < 4; ++m){
      float keep = s4 ? t8[4+m] : t8[m];
      float give = s4 ? t8[m]   : t8[4+m];
      t4[m] = keep + __shfl_xor(give, 16, 64);
    }
    float t2[2];
#pragma unroll
    for (int m = 0; m < 2; ++m){
      float keep = s3 ? t4[2+m] : t4[m];
      float give = s3 ? t4[m]   : t4[2+m];
      t2[m] = keep + __shfl_xor(give, 8, 64);
    }
    float keep = s2 ? t2[1] : t2[0];
    float give = s2 ? t2[0] : t2[1];
    float v = keep + __shfl_xor(give, 4, 64);
    v += __shfl_xor(v, 2, 64);
    v += __shfl_xor(v, 1, 64);
    float hv = __shfl(v, (lane & 15) * 4, 64);
    if (lane < 16) h1[(size_t)n * HIDN + lane] = (_Float16)hv;   // RAW (no dis)
  }
}

// kp2: per-bucket exclusive scan across chunks: one block per bucket, thread per chunk.
__global__ __launch_bounds__(512) void kp2_rowscan(int* __restrict__ M, int* __restrict__ btot){
  __shared__ int s[512];
  const int b = blockIdx.x, t = threadIdx.x;     // b < NBUCK, t < NBLK
  const int idx = t * NBUCK + b;
  int v = M[idx];
  int x = v;
  s[t] = x; __syncthreads();
  for (int d = 1; d < 512; d <<= 1){
    int y = (t >= d) ? s[t - d] : 0;
    __syncthreads();
    x += y; s[t] = x;
    __syncthreads();
  }
  M[idx] = x - v;                 // exclusive over chunks
  if (t == 511) btot[b] = x;      // bucket total
}

// kp2b: exclusive scan of bucket totals -> bbase[NBUCK+1]
__global__ __launch_bounds__(512) void kp2b_bscan(const int* __restrict__ btot, int* __restrict__ bbase){
  __shared__ int s[512];
  const int t = threadIdx.x;
  int v = (t < NBUCK) ? btot[t] : 0;
  int x = v;
  s[t] = x; __syncthreads();
  for (int d = 1; d < 512; d <<= 1){
    int y = (t >= d) ? s[t - d] : 0;
    __syncthreads();
    x += y; s[t] = x;
    __syncthreads();
  }
  if (t < NBUCK) bbase[t] = x - v;
  if (t == NBUCK - 1) bbase[NBUCK] = x;   // == NE
}

// kp3: coarse scatter, packed (c&255)<<17 | src (src < 2^17). Each (bucket,chunk)
// segment written by exactly one block -> lines single-XCD-owned -> L2 write-merge.
__global__ __launch_bounds__(256) void kp3_scatter(const int* __restrict__ row, const int* __restrict__ col,
                                                   const int* __restrict__ M, const int* __restrict__ bbase,
                                                   unsigned* __restrict__ coarse){
  __shared__ int cur[NBUCK];
  const int blk = blockIdx.x, t = threadIdx.x;
  for (int q = t; q < NBUCK; q += 256) cur[q] = bbase[q] + M[blk * NBUCK + q];
  __syncthreads();
  const int e0 = blk * CHUNK;
  for (int i = t; i < CHUNK; i += 256){
    int c = col[e0 + i];
    int r = row[e0 + i];
    int p = atomicAdd(&cur[c >> 8], 1);            // LDS atomic
    coarse[p] = ((unsigned)(c & 255) << 17) | (unsigned)r;
  }
}

// kd: per-node in-degree -> dis, one block per bucket (LDS int histogram).
__global__ __launch_bounds__(1024) void kd_dis(const unsigned* __restrict__ coarse,
                                               const int* __restrict__ bbase,
                                               float* __restrict__ dis){
  __shared__ int cnt[256];
  const int b = blockIdx.x, t = threadIdx.x;
  if (t < 256) cnt[t] = 0;
  __syncthreads();
  const int base = bbase[b];
  const int nreg = bbase[b + 1] - base;
  for (int i = t; i < nreg; i += 1024)
    atomicAdd(&cnt[coarse[base + i] >> 17], 1);
  __syncthreads();
  if (t < 256){
    int n = (b << 8) + t;
    if (n < NN) dis[n] = rsqrtf((float)(cnt[t] + 1));   // +1 self-loop
  }
}

// ---- aggA: layer-1 aggregation DIRECT from coarse bins (no fine sort, no csr).
// Block per bucket; 16-lane group per edge; LDS f32 atomic accumulate into
// acc[256][16]. Epilogue: bias/relu/dropout -> h2s16 (pre-scaled by dis).
__global__ __launch_bounds__(1024) void k_aggA(const unsigned* __restrict__ coarse,
                                               const int* __restrict__ bbase,
                                               const _Float16* __restrict__ h1,
                                               const float* __restrict__ dis,
                                               const float* __restrict__ b1,
                                               _Float16* __restrict__ h2s){
  __shared__ float acc[256 * HIDN];
  const int b = blockIdx.x, t = threadIdx.x;
  for (int q = t; q < 256 * HIDN; q += 1024) acc[q] = 0.f;
  __syncthreads();
  const int base = bbase[b];
  const int nreg = bbase[b + 1] - base;
  const int g = t >> 4, j = t & 15;          // 64 groups x 16 feature-lanes
  unsigned pnext = (g < nreg) ? coarse[base + g] : 0u;
  for (int i = g; i < nreg; i += 64){
    unsigned p = pnext;
    int inext = i + 64;
    pnext = (inext < nreg) ? coarse[base + inext] : 0u;   // prefetch: break load chain
    int d = p >> 17;
    int r = (int)(p & 0x1FFFFu);
    float hv = (float)h1[r * HIDN + j];      // 16 lanes -> one 32B segment (L2-fit)
    atomicAdd(&acc[d * HIDN + j], dis[r] * hv);
  }
  __syncthreads();
  // epilogue: thread covers (dest, 4 features)
  const int d = t >> 2, j0 = (t & 3) * 4;
  const int n = (b << 8) + d;
  if (n < NN){
    float dn = dis[n];
    union { _Float16 f[4]; float2 v; } u;
#pragma unroll
    for (int q = 0; q < 4; ++q){
      int jj = j0 + q;
      float selfh = (float)h1[n * HIDN + jj];
      float v = fmaf(dn, acc[d * HIDN + jj] + dn * selfh, b1[jj]);
      v = fmaxf(v, 0.f);
      unsigned bits = threefry_bits((unsigned)(n * HIDN + jj));
      float kept = (bits & 0x80000000u) ? 0.f : v * 2.f;   // /(1-p) = *2
      u.f[q] = (_Float16)(kept * dn);                       // pre-scale for layer 2
    }
    *(float2*)(h2s + (size_t)n * HIDN + j0) = u.v;
  }
}

// ---- aggB: layer-2 aggregation direct from coarse + W2 matmul + log_softmax ----
__global__ __launch_bounds__(1024) void k_aggB(const unsigned* __restrict__ coarse,
                                               const int* __restrict__ bbase,
                                               const _Float16* __restrict__ h2s,
                                               const float* __restrict__ dis,
                                               const float* __restrict__ W2,
                                               const float* __restrict__ b2,
                                               float* __restrict__ out){
  __shared__ float acc[256 * HIDN];
  const int b = blockIdx.x, t = threadIdx.x;
  for (int q = t; q < 256 * HIDN; q += 1024) acc[q] = 0.f;
  __syncthreads();
  const int base = bbase[b];
  const int nreg = bbase[b + 1] - base;
  const int g = t >> 4, j = t & 15;
  unsigned pnext = (g < nreg) ? coarse[base + g] : 0u;
  for (int i = g; i < nreg; i += 64){
    unsigned p = pnext;
    int inext = i + 64;
    pnext = (inext < nreg) ? coarse[base + inext] : 0u;
    int d = p >> 17;
    int r = (int)(p & 0x1FFFFu);
    atomicAdd(&acc[d * HIDN + j], (float)h2s[r * HIDN + j]);   // table pre-scaled
  }
  __syncthreads();
  // epilogue: wave per dest (16 waves x 16 dests each)
  const int lane = t & 63, w = t >> 6;
  float wc[16];
#pragma unroll
  for (int k = 0; k < 16; ++k) wc[k] = W2[k * NCLS + lane];
  const float bb = b2[lane];
  for (int d = w; d < 256; d += 16){
    int n = (b << 8) + d;
    if (n >= NN) continue;                   // wave-uniform
    float dn = dis[n];
    int jl = lane & 15;
    float aggj = dn * (acc[d * HIDN + jl] + (float)h2s[(size_t)n * HIDN + jl]);
    float s = bb;
#pragma unroll
    for (int k = 0; k < 16; ++k) s = fmaf(__shfl(aggj, k, 64), wc[k], s);
    float m2 = s;
#pragma unroll
    for (int dd = 32; dd; dd >>= 1) m2 = fmaxf(m2, __shfl_xor(m2, dd, 64));
    float ex = __expf(s - m2);
    float sum = ex;
#pragma unroll
    for (int dd = 32; dd; dd >>= 1) sum += __shfl_xor(sum, dd, 64);
    out[(size_t)n * NCLS + lane] = (s - m2) - __logf(sum);
  }
}

// ---------------- launch ----------------
extern "C" void kernel_launch(void* const* d_in, const int* in_sizes, int n_in,
                              void* d_out, int out_size, void* d_ws, size_t ws_size,
                              hipStream_t stream){
  const float* x  = (const float*)d_in[0];
  const int*   ei = (const int*)  d_in[1];
  const float* W1 = (const float*)d_in[2];
  const float* b1 = (const float*)d_in[3];
  const float* W2 = (const float*)d_in[4];
  const float* b2 = (const float*)d_in[5];
  float* out = (float*)d_out;
  const int* row = ei;          // sources
  const int* col = ei + NE;     // destinations

  char* ws = (char*)d_ws;
  int*       M      = (int*)      (ws + 0);          // 800,768 B  coarse matrix
  int*       btot   = (int*)      (ws + 800768);     // 1.6 KB
  int*       bbase  = (int*)      (ws + 802368);     // 1.6 KB
  float*     dis    = (float*)    (ws + 803968);     // 400 KB
  _Float16*  h1     = (_Float16*) (ws + 1203968);    // 3.2 MB  raw x@W1
  _Float16*  h2s    = (_Float16*) (ws + 4403968);    // 3.2 MB  dropout(relu(l1))*dis
  unsigned*  coarse = (unsigned*) (ws + 7603968);    // 12.8 MB bucket-binned edges

  k_front    <<<NBLK + 1024, 256, 0, stream>>>(x, W1, col, M, h1);
  kp2_rowscan<<<NBUCK, 512, 0, stream>>>(M, btot);
  kp2b_bscan <<<1, 512, 0, stream>>>(btot, bbase);
  kp3_scatter<<<NBLK, 256, 0, stream>>>(row, col, M, bbase, coarse);
  kd_dis     <<<NBUCK, 1024, 0, stream>>>(coarse, bbase, dis);
  k_aggA     <<<NBUCK, 1024, 0, stream>>>(coarse, bbase, h1, dis, b1, h2s);
  k_aggB     <<<NBUCK, 1024, 0, stream>>>(coarse, bbase, h2s, dis, W2, b2, out);
}

// Round 7
// 509.342 us; speedup vs baseline: 2.1622x; 2.1622x over previous
//
#include <hip/hip_runtime.h>

#define NN    100000
#define NE    3200000
#define DIMK  512
#define HIDN  16
#define NCLS  64
#define NBUCK 391        // ceil(NN / 256) coarse buckets (dest >> 8)
#define NBLK  512        // coarse-pass chunks
#define CHUNK 6250       // NE / NBLK exactly
#define BCAP  10240      // per-bucket edge cap (mean 8192, sigma ~90 -> >20 sigma)

// ---- threefry2x32-20, JAX partitionable 32-bit path: bits = x0_final ^ x1_final,
// key=(0,42), counter=(0, i). Verified (absmax 0.031).
__device__ __forceinline__ unsigned rotl32(unsigned x, int r){ return (x << r) | (x >> (32 - r)); }

__device__ __forceinline__ unsigned threefry_bits(unsigned i){
  const unsigned k0 = 0u, k1 = 42u;
  const unsigned k2 = 0x1BD11BDAu ^ k0 ^ k1;
  unsigned a = 0u + k0, b = i + k1;
#define TF_R(r) { a += b; b = rotl32(b, (r)); b ^= a; }
  TF_R(13) TF_R(15) TF_R(26) TF_R(6)  a += k1; b += k2 + 1u;
  TF_R(17) TF_R(29) TF_R(16) TF_R(24) a += k2; b += k0 + 2u;
  TF_R(13) TF_R(15) TF_R(26) TF_R(6)  a += k0; b += k1 + 3u;
  TF_R(17) TF_R(29) TF_R(16) TF_R(24) a += k1; b += k2 + 4u;
  TF_R(13) TF_R(15) TF_R(26) TF_R(6)  a += k2; b += k0 + 5u;
#undef TF_R
  return a ^ b;   // keep iff !(bits & 0x80000000)
}

// ---------------- CSR build: deterministic two-level counting sort ----------------
// kp1: coarse histogram per chunk -> M[blk*NBUCK + b]  (LDS atomics only)
__global__ __launch_bounds__(256) void kp1_hist(const int* __restrict__ col, int* __restrict__ M){
  __shared__ int h[NBUCK];
  const int blk = blockIdx.x, t = threadIdx.x;
  for (int q = t; q < NBUCK; q += 256) h[q] = 0;
  __syncthreads();
  const int e0 = blk * CHUNK;
  for (int i = t; i < CHUNK; i += 256)
    atomicAdd(&h[col[e0 + i] >> 8], 1);
  __syncthreads();
  for (int q = t; q < NBUCK; q += 256) M[blk * NBUCK + q] = h[q];
}

// kp2: per-bucket exclusive scan across chunks: one block per bucket, thread per chunk.
__global__ __launch_bounds__(512) void kp2_rowscan(int* __restrict__ M, int* __restrict__ btot){
  __shared__ int s[512];
  const int b = blockIdx.x, t = threadIdx.x;     // b < NBUCK, t < NBLK
  const int idx = t * NBUCK + b;
  int v = M[idx];
  int x = v;
  s[t] = x; __syncthreads();
  for (int d = 1; d < 512; d <<= 1){
    int y = (t >= d) ? s[t - d] : 0;
    __syncthreads();
    x += y; s[t] = x;
    __syncthreads();
  }
  M[idx] = x - v;                 // exclusive over chunks
  if (t == 511) btot[b] = x;      // bucket total
}

// kp2b: exclusive scan of bucket totals -> bbase[NBUCK+1]
__global__ __launch_bounds__(512) void kp2b_bscan(const int* __restrict__ btot, int* __restrict__ bbase){
  __shared__ int s[512];
  const int t = threadIdx.x;
  int v = (t < NBUCK) ? btot[t] : 0;
  int x = v;
  s[t] = x; __syncthreads();
  for (int d = 1; d < 512; d <<= 1){
    int y = (t >= d) ? s[t - d] : 0;
    __syncthreads();
    x += y; s[t] = x;
    __syncthreads();
  }
  if (t < NBUCK) bbase[t] = x - v;
  if (t == NBUCK - 1) bbase[NBUCK] = x;   // == NE
}

// kp3: coarse scatter, packed (c&255)<<17 | src (src < 2^17). Each (bucket,chunk)
// segment written by exactly one block -> lines single-XCD-owned -> L2 write-merge.
__global__ __launch_bounds__(256) void kp3_scatter(const int* __restrict__ row, const int* __restrict__ col,
                                                   const int* __restrict__ M, const int* __restrict__ bbase,
                                                   unsigned* __restrict__ coarse){
  __shared__ int cur[NBUCK];
  const int blk = blockIdx.x, t = threadIdx.x;
  for (int q = t; q < NBUCK; q += 256) cur[q] = bbase[q] + M[blk * NBUCK + q];
  __syncthreads();
  const int e0 = blk * CHUNK;
  for (int i = t; i < CHUNK; i += 256){
    int c = col[e0 + i];
    int r = row[e0 + i];
    int p = atomicAdd(&cur[c >> 8], 1);            // LDS atomic
    coarse[p] = ((unsigned)(c & 255) << 17) | (unsigned)r;
  }
}

// kd: per-node in-degree -> dis, one block per bucket (LDS int histogram).
__global__ __launch_bounds__(1024) void kd_dis(const unsigned* __restrict__ coarse,
                                               const int* __restrict__ bbase,
                                               float* __restrict__ dis){
  __shared__ int cnt[256];
  const int b = blockIdx.x, t = threadIdx.x;
  if (t < 256) cnt[t] = 0;
  __syncthreads();
  const int base = bbase[b];
  const int nreg = bbase[b + 1] - base;
  for (int i = t; i < nreg; i += 1024)
    atomicAdd(&cnt[coarse[base + i] >> 17], 1);
  __syncthreads();
  if (t < 256){
    int n = (b << 8) + t;
    if (n < NN) dis[n] = rsqrtf((float)(cnt[t] + 1));   // +1 self-loop
  }
}

// ---- h1 = x @ W1, epilogue pre-scales by dis[n], stores FP16: hs16 = (f16)(h1*dis) ----
// fp16 table = 3.2 MB -> fits every XCD's 4 MB L2 -> gathers L2-resident.
__global__ __launch_bounds__(256) void k_gemm1(const float* __restrict__ x,
                                               const float* __restrict__ W1,
                                               const float* __restrict__ dis,
                                               _Float16* __restrict__ hs16){
  const int lane = threadIdx.x & 63;
  const int wid  = (blockIdx.x * blockDim.x + threadIdx.x) >> 6;
  const int nw   = (gridDim.x * blockDim.x) >> 6;
  const bool s5 = (lane & 32) != 0;
  const bool s4 = (lane & 16) != 0;
  const bool s3 = (lane & 8)  != 0;
  const bool s2 = (lane & 4)  != 0;

  float4 w4[8][4];
  const float4* W1v = (const float4*)W1;
#pragma unroll
  for (int k = 0; k < 8; ++k)
#pragma unroll
    for (int jj = 0; jj < 4; ++jj)
      w4[k][jj] = W1v[(lane * 8 + k) * 4 + jj];

  for (int n = wid; n < NN; n += nw){
    const float4* xp = (const float4*)(x + (size_t)n * DIMK + lane * 8);
    float4 xa = xp[0], xb = xp[1];
    float xv[8] = {xa.x, xa.y, xa.z, xa.w, xb.x, xb.y, xb.z, xb.w};
    float acc[16];
#pragma unroll
    for (int j = 0; j < 16; ++j) acc[j] = 0.f;
#pragma unroll
    for (int k = 0; k < 8; ++k){
      float xk = xv[k];
#pragma unroll
      for (int jj = 0; jj < 4; ++jj){
        acc[jj*4+0] = fmaf(xk, w4[k][jj].x, acc[jj*4+0]);
        acc[jj*4+1] = fmaf(xk, w4[k][jj].y, acc[jj*4+1]);
        acc[jj*4+2] = fmaf(xk, w4[k][jj].z, acc[jj*4+2]);
        acc[jj*4+3] = fmaf(xk, w4[k][jj].w, acc[jj*4+3]);
      }
    }
    float t8[8];
#pragma unroll
    for (int m = 0; m < 8; ++m){
      float keep = s5 ? acc[8+m] : acc[m];
      float give = s5 ? acc[m]   : acc[8+m];
      t8[m] = keep + __shfl_xor(give, 32, 64);
    }
    float t4[4];
#pragma unroll
    for (int m = 0; m < 4; ++m){
      float keep = s4 ? t8[4+m] : t8[m];
      float give = s4 ? t8[m]   : t8[4+m];
      t4[m] = keep + __shfl_xor(give, 16, 64);
    }
    float t2[2];
#pragma unroll
    for (int m = 0; m < 2; ++m){
      float keep = s3 ? t4[2+m] : t4[m];
      float give = s3 ? t4[m]   : t4[2+m];
      t2[m] = keep + __shfl_xor(give, 8, 64);
    }
    float keep = s2 ? t2[1] : t2[0];
    float give = s2 ? t2[0] : t2[1];
    float v = keep + __shfl_xor(give, 4, 64);
    v += __shfl_xor(v, 2, 64);
    v += __shfl_xor(v, 1, 64);
    float hv = __shfl(v, (lane & 15) * 4, 64);
    if (lane < 16) hs16[(size_t)n * HIDN + lane] = (_Float16)(hv * dis[n]);
  }
}

// ---- k_sortagg1: per-bucket fine sort IN LDS + layer-1 aggregation fused ----
// Build sorted edge list in LDS (count/scan/rank, int LDS atomics); write
// csr/dstart/dcnt coalesced (for layer-2); then 64x16-lane groups aggregate
// each dest's contiguous LDS list with unroll-2 independent L2 gathers.
// Epilogue: bias/relu/dropout -> h2s16 (pre-scaled by dis for layer 2).
__global__ __launch_bounds__(1024) void k_sortagg1(const unsigned* __restrict__ coarse,
                                                   const int* __restrict__ bbase,
                                                   const _Float16* __restrict__ hs16,
                                                   const float* __restrict__ dis,
                                                   const float* __restrict__ b1,
                                                   int* __restrict__ csr,
                                                   int* __restrict__ dstart,
                                                   int* __restrict__ dcnt,
                                                   _Float16* __restrict__ h2s16){
  __shared__ int ldsCsr[BCAP];
  __shared__ int cnt[256], ofs[256], rk[256], s[256];
  const int b = blockIdx.x, t = threadIdx.x;
  const int base = bbase[b];
  const int nreg = min(bbase[b + 1] - base, BCAP);
  if (t < 256){ cnt[t] = 0; rk[t] = 0; }
  __syncthreads();
  // pass 1: per-dest count
  for (int i = t; i < nreg; i += 1024)
    atomicAdd(&cnt[coarse[base + i] >> 17], 1);
  __syncthreads();
  // exclusive scan of cnt (first 256 threads)
  int deg = 0, x = 0;
  if (t < 256){ deg = cnt[t]; x = deg; s[t] = x; }
  __syncthreads();
  for (int d = 1; d < 256; d <<= 1){
    int y = 0;
    if (t < 256 && t >= d) y = s[t - d];
    __syncthreads();
    if (t < 256){ x += y; s[t] = x; }
    __syncthreads();
  }
  if (t < 256) ofs[t] = x - deg;
  __syncthreads();
  // pass 2: rank & place into LDS sorted list
  for (int i = t; i < nreg; i += 1024){
    unsigned p = coarse[base + i];
    int l = p >> 17;
    int q = atomicAdd(&rk[l], 1);
    ldsCsr[ofs[l] + q] = (int)(p & 0x1FFFFu);
  }
  // metadata writeback (no dependence on ldsCsr)
  if (t < 256){
    int n = (b << 8) + t;
    if (n < NN){ dstart[n] = base + ofs[t]; dcnt[n] = cnt[t]; }
  }
  __syncthreads();
  // sorted csr writeback (coalesced) for layer-2
  for (int q = t; q < nreg; q += 1024) csr[base + q] = ldsCsr[q];
  // ---- aggregation: 64 groups x 16 feature-lanes; 4 dests per group ----
  const int g = t >> 4, j = t & 15;
  for (int d = g; d < 256; d += 64){
    const int n = (b << 8) + d;
    if (n >= NN) break;
    const int st = ofs[d], cn = cnt[d];
    float acc = 0.f;
    int i = 0;
    for (; i + 2 <= cn; i += 2){
      int r0 = ldsCsr[st + i];
      int r1 = ldsCsr[st + i + 1];
      float a0 = (float)hs16[r0 * HIDN + j];   // independent L2 gathers
      float a1 = (float)hs16[r1 * HIDN + j];
      acc += a0 + a1;
    }
    if (i < cn) acc += (float)hs16[ldsCsr[st + i] * HIDN + j];
    float dn = dis[n];
    float v = fmaf(dn, acc + (float)hs16[(size_t)n * HIDN + j], b1[j]);
    v = fmaxf(v, 0.f);
    unsigned bits = threefry_bits((unsigned)(n * HIDN + j));
    float kept = (bits & 0x80000000u) ? 0.f : v * 2.f;   // /(1-p) = *2
    h2s16[(size_t)n * HIDN + j] = (_Float16)(kept * dn);  // pre-scale for layer 2
  }
}

// ---- layer-2 pull aggregation + W2 matmul + log_softmax fused: wave per node ----
__global__ __launch_bounds__(256) void k_agg2out(const int* __restrict__ csr,
                                                 const int* __restrict__ dstart,
                                                 const int* __restrict__ dcnt,
                                                 const _Float16* __restrict__ h2s16,
                                                 const float* __restrict__ dis,
                                                 const float* __restrict__ W2,
                                                 const float* __restrict__ b2,
                                                 float* __restrict__ out){
  const int lane = threadIdx.x & 63;
  const int wid  = (blockIdx.x * blockDim.x + threadIdx.x) >> 6;
  const int nw   = (gridDim.x * blockDim.x) >> 6;
  const int j  = lane & 15;
  const int c4 = lane >> 4;
  float wc[16];
#pragma unroll
  for (int k = 0; k < 16; ++k) wc[k] = W2[k * NCLS + lane];
  const float bb = b2[lane];
  for (int n = wid; n < NN; n += nw){
    const int start = dstart[n];
    const int end   = start + dcnt[n];
    float acc = 0.f;
    for (int base = start; base < end; base += 64){
      const int m = min(end - base, 64);
      int rv = (lane < m) ? csr[base + lane] : 0;
      const int itmax = (m + 3) >> 2;
      for (int it = 0; it < itmax; ++it){
        int e = it * 4 + c4;
        int r = __shfl(rv, e & 63, 64);
        if (e < m) acc += (float)h2s16[r * HIDN + j];
      }
    }
    acc += __shfl_xor(acc, 16, 64);
    acc += __shfl_xor(acc, 32, 64);
    float dn = dis[n];
    float aggj = dn * (acc + (float)h2s16[(size_t)n * HIDN + j]);
    float s = bb;
#pragma unroll
    for (int k = 0; k < 16; ++k) s = fmaf(__shfl(aggj, k, 64), wc[k], s);
    float m2 = s;
#pragma unroll
    for (int d = 32; d; d >>= 1) m2 = fmaxf(m2, __shfl_xor(m2, d, 64));
    float ex = __expf(s - m2);
    float sum = ex;
#pragma unroll
    for (int d = 32; d; d >>= 1) sum += __shfl_xor(sum, d, 64);
    out[(size_t)n * NCLS + lane] = (s - m2) - __logf(sum);
  }
}

// ---------------- launch ----------------
extern "C" void kernel_launch(void* const* d_in, const int* in_sizes, int n_in,
                              void* d_out, int out_size, void* d_ws, size_t ws_size,
                              hipStream_t stream){
  const float* x  = (const float*)d_in[0];
  const int*   ei = (const int*)  d_in[1];
  const float* W1 = (const float*)d_in[2];
  const float* b1 = (const float*)d_in[3];
  const float* W2 = (const float*)d_in[4];
  const float* b2 = (const float*)d_in[5];
  float* out = (float*)d_out;
  const int* row = ei;          // sources
  const int* col = ei + NE;     // destinations

  char* ws = (char*)d_ws;
  int*       M      = (int*)      (ws + 0);          // 800,768 B  coarse matrix
  int*       btot   = (int*)      (ws + 800768);     // 1.6 KB
  int*       bbase  = (int*)      (ws + 802368);     // 1.6 KB
  int*       dstart = (int*)      (ws + 803968);     // 400 KB
  int*       dcnt   = (int*)      (ws + 1203968);    // 400 KB
  float*     dis    = (float*)    (ws + 1603968);    // 400 KB
  int*       csr    = (int*)      (ws + 2003968);    // 12.8 MB
  unsigned*  coarse = (unsigned*) (ws + 14803968);   // 12.8 MB
  _Float16*  hs16   = (_Float16*) (ws + 27603968);   // 3.2 MB
  _Float16*  h2s16  = (_Float16*) (ws + 30803968);   // 3.2 MB

  kp1_hist   <<<NBLK, 256, 0, stream>>>(col, M);
  kp2_rowscan<<<NBUCK, 512, 0, stream>>>(M, btot);
  kp2b_bscan <<<1, 512, 0, stream>>>(btot, bbase);
  kp3_scatter<<<NBLK, 256, 0, stream>>>(row, col, M, bbase, coarse);
  kd_dis     <<<NBUCK, 1024, 0, stream>>>(coarse, bbase, dis);
  k_gemm1    <<<1024, 256, 0, stream>>>(x, W1, dis, hs16);
  k_sortagg1 <<<NBUCK, 1024, 0, stream>>>(coarse, bbase, hs16, dis, b1, csr, dstart, dcnt, h2s16);
  k_agg2out  <<<2048, 256, 0, stream>>>(csr, dstart, dcnt, h2s16, dis, W2, b2, out);
}

// Round 8
// 507.646 us; speedup vs baseline: 2.1694x; 1.0033x over previous
//
#include <hip/hip_runtime.h>

#define NN    100000
#define NE    3200000
#define DIMK  512
#define HIDN  16
#define NCLS  64
#define NBUCK 391        // ceil(NN / 256) coarse buckets (dest >> 8)
#define NBLK  512        // coarse-pass chunks
#define CHUNK 6250       // NE / NBLK exactly
#define BCAP  10240      // per-bucket edge cap (mean 8192, sigma ~90 -> >20 sigma)

// ---- threefry2x32-20, JAX partitionable 32-bit path: bits = x0_final ^ x1_final,
// key=(0,42), counter=(0, i). Verified (absmax 0.031).
__device__ __forceinline__ unsigned rotl32(unsigned x, int r){ return (x << r) | (x >> (32 - r)); }

__device__ __forceinline__ unsigned threefry_bits(unsigned i){
  const unsigned k0 = 0u, k1 = 42u;
  const unsigned k2 = 0x1BD11BDAu ^ k0 ^ k1;
  unsigned a = 0u + k0, b = i + k1;
#define TF_R(r) { a += b; b = rotl32(b, (r)); b ^= a; }
  TF_R(13) TF_R(15) TF_R(26) TF_R(6)  a += k1; b += k2 + 1u;
  TF_R(17) TF_R(29) TF_R(16) TF_R(24) a += k2; b += k0 + 2u;
  TF_R(13) TF_R(15) TF_R(26) TF_R(6)  a += k0; b += k1 + 3u;
  TF_R(17) TF_R(29) TF_R(16) TF_R(24) a += k1; b += k2 + 4u;
  TF_R(13) TF_R(15) TF_R(26) TF_R(6)  a += k2; b += k0 + 5u;
#undef TF_R
  return a ^ b;   // keep iff !(bits & 0x80000000)
}

// ---------------- CSR build: deterministic two-level counting sort ----------------
// kp1: coarse histogram per chunk -> M[blk*NBUCK + b]  (LDS atomics only)
__global__ __launch_bounds__(256) void kp1_hist(const int* __restrict__ col, int* __restrict__ M){
  __shared__ int h[NBUCK];
  const int blk = blockIdx.x, t = threadIdx.x;
  for (int q = t; q < NBUCK; q += 256) h[q] = 0;
  __syncthreads();
  const int e0 = blk * CHUNK;
  for (int i = t; i < CHUNK; i += 256)
    atomicAdd(&h[col[e0 + i] >> 8], 1);
  __syncthreads();
  for (int q = t; q < NBUCK; q += 256) M[blk * NBUCK + q] = h[q];
}

// kp2: per-bucket exclusive scan across chunks: one block per bucket, thread per chunk.
__global__ __launch_bounds__(512) void kp2_rowscan(int* __restrict__ M, int* __restrict__ btot){
  __shared__ int s[512];
  const int b = blockIdx.x, t = threadIdx.x;     // b < NBUCK, t < NBLK
  const int idx = t * NBUCK + b;
  int v = M[idx];
  int x = v;
  s[t] = x; __syncthreads();
  for (int d = 1; d < 512; d <<= 1){
    int y = (t >= d) ? s[t - d] : 0;
    __syncthreads();
    x += y; s[t] = x;
    __syncthreads();
  }
  M[idx] = x - v;                 // exclusive over chunks
  if (t == 511) btot[b] = x;      // bucket total
}

// kp2b: exclusive scan of bucket totals -> bbase[NBUCK+1]
__global__ __launch_bounds__(512) void kp2b_bscan(const int* __restrict__ btot, int* __restrict__ bbase){
  __shared__ int s[512];
  const int t = threadIdx.x;
  int v = (t < NBUCK) ? btot[t] : 0;
  int x = v;
  s[t] = x; __syncthreads();
  for (int d = 1; d < 512; d <<= 1){
    int y = (t >= d) ? s[t - d] : 0;
    __syncthreads();
    x += y; s[t] = x;
    __syncthreads();
  }
  if (t < NBUCK) bbase[t] = x - v;
  if (t == NBUCK - 1) bbase[NBUCK] = x;   // == NE
}

// kp3: coarse scatter, packed (c&255)<<17 | src (src < 2^17). Each (bucket,chunk)
// segment written by exactly one block -> lines single-XCD-owned -> L2 write-merge.
__global__ __launch_bounds__(256) void kp3_scatter(const int* __restrict__ row, const int* __restrict__ col,
                                                   const int* __restrict__ M, const int* __restrict__ bbase,
                                                   unsigned* __restrict__ coarse){
  __shared__ int cur[NBUCK];
  const int blk = blockIdx.x, t = threadIdx.x;
  for (int q = t; q < NBUCK; q += 256) cur[q] = bbase[q] + M[blk * NBUCK + q];
  __syncthreads();
  const int e0 = blk * CHUNK;
  for (int i = t; i < CHUNK; i += 256){
    int c = col[e0 + i];
    int r = row[e0 + i];
    int p = atomicAdd(&cur[c >> 8], 1);            // LDS atomic
    coarse[p] = ((unsigned)(c & 255) << 17) | (unsigned)r;
  }
}

// kd_meta: per-bucket count + scan -> dstart/dcnt/dis (one coarse pass).
// Both agg kernels then skip their own count/scan and only rank-place.
__global__ __launch_bounds__(1024) void kd_meta(const unsigned* __restrict__ coarse,
                                                const int* __restrict__ bbase,
                                                int* __restrict__ dstart,
                                                int* __restrict__ dcnt,
                                                float* __restrict__ dis){
  __shared__ int cnt[256], s[256];
  const int b = blockIdx.x, t = threadIdx.x;
  if (t < 256) cnt[t] = 0;
  __syncthreads();
  const int base = bbase[b];
  const int nreg = bbase[b + 1] - base;
  for (int i = t; i < nreg; i += 1024)
    atomicAdd(&cnt[coarse[base + i] >> 17], 1);
  __syncthreads();
  int deg = 0, x = 0;
  if (t < 256){ deg = cnt[t]; x = deg; s[t] = x; }
  __syncthreads();
  for (int d = 1; d < 256; d <<= 1){
    int y = 0;
    if (t < 256 && t >= d) y = s[t - d];
    __syncthreads();
    if (t < 256){ x += y; s[t] = x; }
    __syncthreads();
  }
  if (t < 256){
    int n = (b << 8) + t;
    if (n < NN){
      dstart[n] = base + (x - deg);
      dcnt[n]   = deg;
      dis[n]    = rsqrtf((float)(deg + 1));   // +1 self-loop
    }
  }
}

// ---- h1 = x @ W1, epilogue pre-scales by dis[n], stores FP16: hs16 = (f16)(h1*dis) ----
// fp16 table = 3.2 MB -> fits every XCD's 4 MB L2 -> gathers L2-resident.
__global__ __launch_bounds__(256) void k_gemm1(const float* __restrict__ x,
                                               const float* __restrict__ W1,
                                               const float* __restrict__ dis,
                                               _Float16* __restrict__ hs16){
  const int lane = threadIdx.x & 63;
  const int wid  = (blockIdx.x * blockDim.x + threadIdx.x) >> 6;
  const int nw   = (gridDim.x * blockDim.x) >> 6;
  const bool s5 = (lane & 32) != 0;
  const bool s4 = (lane & 16) != 0;
  const bool s3 = (lane & 8)  != 0;
  const bool s2 = (lane & 4)  != 0;

  float4 w4[8][4];
  const float4* W1v = (const float4*)W1;
#pragma unroll
  for (int k = 0; k < 8; ++k)
#pragma unroll
    for (int jj = 0; jj < 4; ++jj)
      w4[k][jj] = W1v[(lane * 8 + k) * 4 + jj];

  for (int n = wid; n < NN; n += nw){
    const float4* xp = (const float4*)(x + (size_t)n * DIMK + lane * 8);
    float4 xa = xp[0], xb = xp[1];
    float xv[8] = {xa.x, xa.y, xa.z, xa.w, xb.x, xb.y, xb.z, xb.w};
    float acc[16];
#pragma unroll
    for (int j = 0; j < 16; ++j) acc[j] = 0.f;
#pragma unroll
    for (int k = 0; k < 8; ++k){
      float xk = xv[k];
#pragma unroll
      for (int jj = 0; jj < 4; ++jj){
        acc[jj*4+0] = fmaf(xk, w4[k][jj].x, acc[jj*4+0]);
        acc[jj*4+1] = fmaf(xk, w4[k][jj].y, acc[jj*4+1]);
        acc[jj*4+2] = fmaf(xk, w4[k][jj].z, acc[jj*4+2]);
        acc[jj*4+3] = fmaf(xk, w4[k][jj].w, acc[jj*4+3]);
      }
    }
    float t8[8];
#pragma unroll
    for (int m = 0; m < 8; ++m){
      float keep = s5 ? acc[8+m] : acc[m];
      float give = s5 ? acc[m]   : acc[8+m];
      t8[m] = keep + __shfl_xor(give, 32, 64);
    }
    float t4[4];
#pragma unroll
    for (int m = 0; m < 4; ++m){
      float keep = s4 ? t8[4+m] : t8[m];
      float give = s4 ? t8[m]   : t8[4+m];
      t4[m] = keep + __shfl_xor(give, 16, 64);
    }
    float t2[2];
#pragma unroll
    for (int m = 0; m < 2; ++m){
      float keep = s3 ? t4[2+m] : t4[m];
      float give = s3 ? t4[m]   : t4[2+m];
      t2[m] = keep + __shfl_xor(give, 8, 64);
    }
    float keep = s2 ? t2[1] : t2[0];
    float give = s2 ? t2[0] : t2[1];
    float v = keep + __shfl_xor(give, 4, 64);
    v += __shfl_xor(v, 2, 64);
    v += __shfl_xor(v, 1, 64);
    float hv = __shfl(v, (lane & 15) * 4, 64);
    if (lane < 16) hs16[(size_t)n * HIDN + lane] = (_Float16)(hv * dis[n]);
  }
}

// ---- k_sortagg1: per-bucket rank-place (meta precomputed) + layer-1 agg fused ----
// No count/scan pass (kd_meta did it); no global csr writeback (agg2b re-places).
__global__ __launch_bounds__(1024) void k_sortagg1(const unsigned* __restrict__ coarse,
                                                   const int* __restrict__ bbase,
                                                   const int* __restrict__ dstart,
                                                   const int* __restrict__ dcnt,
                                                   const _Float16* __restrict__ hs16,
                                                   const float* __restrict__ dis,
                                                   const float* __restrict__ b1,
                                                   _Float16* __restrict__ h2s16){
  __shared__ int ldsCsr[BCAP];
  __shared__ int ofs[256], cnt[256], rk[256];
  const int b = blockIdx.x, t = threadIdx.x;
  const int base = bbase[b];
  const int nreg = min(bbase[b + 1] - base, BCAP);
  if (t < 256){
    int n = (b << 8) + t;
    rk[t] = 0;
    if (n < NN){ ofs[t] = dstart[n] - base; cnt[t] = dcnt[n]; }
    else       { ofs[t] = 0;               cnt[t] = 0; }
  }
  __syncthreads();
  // rank & place into LDS sorted list (1 LDS int atomic per edge)
  for (int i = t; i < nreg; i += 1024){
    unsigned p = coarse[base + i];
    int l = p >> 17;
    int q = atomicAdd(&rk[l], 1);
    ldsCsr[ofs[l] + q] = (int)(p & 0x1FFFFu);
  }
  __syncthreads();
  // aggregation: 64 groups x 16 feature-lanes; 4 dests per group
  const int g = t >> 4, j = t & 15;
  for (int d = g; d < 256; d += 64){
    const int n = (b << 8) + d;
    if (n >= NN) break;
    const int st = ofs[d], cn = cnt[d];
    float acc = 0.f;
    int i = 0;
    for (; i + 2 <= cn; i += 2){
      int r0 = ldsCsr[st + i];
      int r1 = ldsCsr[st + i + 1];
      float a0 = (float)hs16[r0 * HIDN + j];   // independent L2 gathers
      float a1 = (float)hs16[r1 * HIDN + j];
      acc += a0 + a1;
    }
    if (i < cn) acc += (float)hs16[ldsCsr[st + i] * HIDN + j];
    float dn = dis[n];
    float v = fmaf(dn, acc + (float)hs16[(size_t)n * HIDN + j], b1[j]);
    v = fmaxf(v, 0.f);
    unsigned bits = threefry_bits((unsigned)(n * HIDN + j));
    float kept = (bits & 0x80000000u) ? 0.f : v * 2.f;   // /(1-p) = *2
    h2s16[(size_t)n * HIDN + j] = (_Float16)(kept * dn);  // pre-scale for layer 2
  }
}

// ---- k_agg2b: per-bucket rank-place + layer-2 agg + W2 matmul + log_softmax ----
// Rank order differs from sortagg1's (atomic race) but aggregation is a sum.
__global__ __launch_bounds__(1024) void k_agg2b(const unsigned* __restrict__ coarse,
                                                const int* __restrict__ bbase,
                                                const int* __restrict__ dstart,
                                                const int* __restrict__ dcnt,
                                                const _Float16* __restrict__ h2s16,
                                                const float* __restrict__ dis,
                                                const float* __restrict__ W2,
                                                const float* __restrict__ b2,
                                                float* __restrict__ out){
  __shared__ int ldsCsr[BCAP];
  __shared__ int ofs[256], cnt[256], rk[256];
  __shared__ float accT[256 * HIDN];
  const int b = blockIdx.x, t = threadIdx.x;
  const int base = bbase[b];
  const int nreg = min(bbase[b + 1] - base, BCAP);
  if (t < 256){
    int n = (b << 8) + t;
    rk[t] = 0;
    if (n < NN){ ofs[t] = dstart[n] - base; cnt[t] = dcnt[n]; }
    else       { ofs[t] = 0;               cnt[t] = 0; }
  }
  __syncthreads();
  for (int i = t; i < nreg; i += 1024){
    unsigned p = coarse[base + i];
    int l = p >> 17;
    int q = atomicAdd(&rk[l], 1);
    ldsCsr[ofs[l] + q] = (int)(p & 0x1FFFFu);
  }
  __syncthreads();
  // aggregation into registers, then exclusive LDS tile (no atomics)
  const int g = t >> 4, j = t & 15;
  for (int d = g; d < 256; d += 64){
    const int n = (b << 8) + d;
    float acc = 0.f;
    if (n < NN){
      const int st = ofs[d], cn = cnt[d];
      int i = 0;
      for (; i + 2 <= cn; i += 2){
        int r0 = ldsCsr[st + i];
        int r1 = ldsCsr[st + i + 1];
        acc += (float)h2s16[r0 * HIDN + j] + (float)h2s16[r1 * HIDN + j];
      }
      if (i < cn) acc += (float)h2s16[ldsCsr[st + i] * HIDN + j];
    }
    accT[d * HIDN + j] = acc;
  }
  __syncthreads();
  // epilogue: 16 waves x 16 dests each; lane = class
  const int lane = t & 63, w = t >> 6;
  float wc[16];
#pragma unroll
  for (int k = 0; k < 16; ++k) wc[k] = W2[k * NCLS + lane];
  const float bb = b2[lane];
  for (int d = w; d < 256; d += 16){
    int n = (b << 8) + d;
    if (n >= NN) continue;                   // wave-uniform
    float dn = dis[n];
    int jl = lane & 15;
    float aggj = dn * (accT[d * HIDN + jl] + (float)h2s16[(size_t)n * HIDN + jl]);
    float s = bb;
#pragma unroll
    for (int k = 0; k < 16; ++k) s = fmaf(__shfl(aggj, k, 64), wc[k], s);
    float m2 = s;
#pragma unroll
    for (int dd = 32; dd; dd >>= 1) m2 = fmaxf(m2, __shfl_xor(m2, dd, 64));
    float ex = __expf(s - m2);
    float sum = ex;
#pragma unroll
    for (int dd = 32; dd; dd >>= 1) sum += __shfl_xor(sum, dd, 64);
    out[(size_t)n * NCLS + lane] = (s - m2) - __logf(sum);
  }
}

// ---------------- launch ----------------
extern "C" void kernel_launch(void* const* d_in, const int* in_sizes, int n_in,
                              void* d_out, int out_size, void* d_ws, size_t ws_size,
                              hipStream_t stream){
  const float* x  = (const float*)d_in[0];
  const int*   ei = (const int*)  d_in[1];
  const float* W1 = (const float*)d_in[2];
  const float* b1 = (const float*)d_in[3];
  const float* W2 = (const float*)d_in[4];
  const float* b2 = (const float*)d_in[5];
  float* out = (float*)d_out;
  const int* row = ei;          // sources
  const int* col = ei + NE;     // destinations

  char* ws = (char*)d_ws;
  int*       M      = (int*)      (ws + 0);          // 800,768 B  coarse matrix
  int*       btot   = (int*)      (ws + 800768);     // 1.6 KB
  int*       bbase  = (int*)      (ws + 802368);     // 1.6 KB
  int*       dstart = (int*)      (ws + 803968);     // 400 KB
  int*       dcnt   = (int*)      (ws + 1203968);    // 400 KB
  float*     dis    = (float*)    (ws + 1603968);    // 400 KB
  unsigned*  coarse = (unsigned*) (ws + 2003968);    // 12.8 MB bucket-binned edges
  _Float16*  hs16   = (_Float16*) (ws + 14803968);   // 3.2 MB
  _Float16*  h2s16  = (_Float16*) (ws + 18003968);   // 3.2 MB

  kp1_hist   <<<NBLK, 256, 0, stream>>>(col, M);
  kp2_rowscan<<<NBUCK, 512, 0, stream>>>(M, btot);
  kp2b_bscan <<<1, 512, 0, stream>>>(btot, bbase);
  kp3_scatter<<<NBLK, 256, 0, stream>>>(row, col, M, bbase, coarse);
  kd_meta    <<<NBUCK, 1024, 0, stream>>>(coarse, bbase, dstart, dcnt, dis);
  k_gemm1    <<<1024, 256, 0, stream>>>(x, W1, dis, hs16);
  k_sortagg1 <<<NBUCK, 1024, 0, stream>>>(coarse, bbase, dstart, dcnt, hs16, dis, b1, h2s16);
  k_agg2b    <<<NBUCK, 1024, 0, stream>>>(coarse, bbase, dstart, dcnt, h2s16, dis, W2, b2, out);
}